// Round 16
// baseline (35.739 us; speedup 1.0000x reference)
//
#include <hip/hip_runtime.h>
#include <hip/hip_bf16.h>

// Fused 3-layer GCN + mean-pool + mask, FP8(e4m3), single main kernel.
//   K0 prep_w: W1,W2 -> fragment-ordered fp8 in device-global g_wf (16 WGs)
//   K1 gcn_all: x-stream + A-build + 4 GEMMs + BN + pool + mask, one WG/graph
// Round-16 (on r14's 31.5us, reverting r15's neutral splits): G0's A-operand
// comes STRAIGHT from global x -> registers -> fp8 fragments (pk8), skipping
// the whole x->Y0 LDS staging pass (4096 ds_writes + 16 ds_reads/wave) and
// turning the WG-wide x barrier-drain into per-wave vmcnt waits. W1 fragment
// loads moved into PH-B (L2-hot; overlap the An-decode VALU) to keep VGPR<=128.
// 6 barriers: P0 | atomics | decode+G0 | G1 | G2 | G3 | OUT.
//
// LDS (62468 B): An[0,16K) | Y0[16K,32K) | X0[32K,48K) |
//   cnt[48K,56K) u32[2048] | misc @56K+1.5K

#define NGRAPH 512
#define EPG 1024
#define NEDGE (NGRAPH * EPG)
#define NEGV -10000000000.0f
#define LDS_MAIN 62468

typedef float f32x16 __attribute__((ext_vector_type(16)));
typedef float f32x4  __attribute__((ext_vector_type(4)));

#define MFMA8(a, b, c) __builtin_amdgcn_mfma_f32_32x32x16_fp8_fp8(a, b, c, 0, 0, 0)

__device__ unsigned char g_wf[32768];   // fp8 W1/W2 fragment buffer

// 128B rows; XOR row into the 8B-slot bits -> 2-way max on b64 reads
__device__ __forceinline__ unsigned swz8(unsigned row, unsigned byte_in_row) {
  return ((row << 7) + byte_in_row) ^ ((row & 15u) << 3);
}

__device__ __forceinline__ unsigned pk4(float a, float b, float c, float d) {
  int r = __builtin_amdgcn_cvt_pk_fp8_f32(a, b, 0, false);
  r = __builtin_amdgcn_cvt_pk_fp8_f32(c, d, r, true);
  return (unsigned)r;
}

__device__ __forceinline__ long pk8(f32x4 u, f32x4 v) {
  union { uint2 u2; long l; } t;
  t.u2.x = pk4(u[0], u[1], u[2], u[3]);
  t.u2.y = pk4(v[0], v[1], v[2], v[3]);
  return t.l;
}

// W [fi][fo] f32 -> fragment-ordered fp8 W^T, 8B per (layer,nt,ks,lane)
__global__ void prep_w(const float* __restrict__ W1, const float* __restrict__ W2) {
  int gid = blockIdx.x * 256 + threadIdx.x;     // 0..4095, 8 fp8 each
  int lyr = gid >> 11, r = gid & 2047;
  int lane = r & 63, ks = (r >> 6) & 7, nt = r >> 9;
  const float* W = lyr ? W2 : W1;
  int fo = nt * 32 + (lane & 31);
  int k0 = ks * 16 + (lane >> 5) * 8;
  uint2 o;
  o.x = pk4(W[(k0 + 0) * 128 + fo], W[(k0 + 1) * 128 + fo],
            W[(k0 + 2) * 128 + fo], W[(k0 + 3) * 128 + fo]);
  o.y = pk4(W[(k0 + 4) * 128 + fo], W[(k0 + 5) * 128 + fo],
            W[(k0 + 6) * 128 + fo], W[(k0 + 7) * 128 + fo]);
  ((uint2*)g_wf)[gid] = o;
}

__global__ __launch_bounds__(512, 4) void gcn_all(
    const float* __restrict__ x, const int* __restrict__ ei,
    const float* __restrict__ b1v, const float* __restrict__ g1v,
    const float* __restrict__ be1v, const float* __restrict__ rm1v,
    const float* __restrict__ rv1v,
    const float* __restrict__ b2v, const float* __restrict__ g2v,
    const float* __restrict__ be2v, const float* __restrict__ rm2v,
    const float* __restrict__ rv2v,
    const float* __restrict__ W3g, const float* __restrict__ b3v,
    float* __restrict__ out) {
  extern __shared__ char sm[];
  char* AnB = sm;                                // fp8 A_norm[128][128] swz
  char* Y0  = sm + 16384;                        // ping buffer (H1)
  char* X0  = sm + 32768;                        // pong buffer
  unsigned* cntW  = (unsigned*)(sm + 49152);     // u4 edge counts [2048 words]
  float*    dis   = (float*)(sm + 57344);
  unsigned* deg   = (unsigned*)(sm + 57856);
  unsigned* conn  = (unsigned*)(sm + 58368);
  float*    csumE = (float*)(sm + 58880);        // edge part of column sum
  float*    scl1  = (float*)(sm + 59392);
  float*    shf1  = (float*)(sm + 59904);
  float*    scl2  = (float*)(sm + 60416);
  float*    shf2  = (float*)(sm + 60928);
  float*    vred  = (float*)(sm + 61440);
  int*      minid = (int*)(sm + 62464);

  const int tid = threadIdx.x;                   // 0..511, 8 waves
  const int g   = blockIdx.x;
  const int lane = tid & 63;
  const int wid  = tid >> 6;                     // 0..7
  const int l31  = lane & 31;
  const int hi   = lane >> 5;
  const int mt   = wid >> 1;                     // A-row tile 0..3
  const int nt0  = (wid & 1) * 2;                // B tiles nt0, nt0+1

  // ---- kernel-top global loads: this lane's own x row-slice + edges ----
  // G0's A-fragment rows are wave-local: row = mt*32+l31, cols ks*16+hi*8..+8.
  const float* xrow = x + (size_t)g * 16384 + (mt * 32 + l31) * 128;
  f32x4 xa[8], xb[8];
#pragma unroll
  for (int ks = 0; ks < 8; ++ks) {
    xa[ks] = *(const f32x4*)(xrow + ks * 16 + hi * 8);
    xb[ks] = *(const f32x4*)(xrow + ks * 16 + hi * 8 + 4);
  }
  int es[2], ed[2];
#pragma unroll
  for (int j = 0; j < 2; ++j) {
    int e = g * EPG + tid + 512 * j;
    es[j] = ei[e] & 127;
    ed[j] = ei[NEDGE + e] & 127;
  }

  // ---- P0: zero cnt, init misc + BN params (no x dependency) ----
  {
    uint4 z; z.x = 0; z.y = 0; z.z = 0; z.w = 0;
    ((uint4*)cntW)[tid] = z;
  }
  if (tid < 128) {
    deg[tid] = 1u; conn[tid] = 0u; csumE[tid] = 0.f; vred[tid] = 0.f;
    float s1 = rsqrtf(rv1v[tid] + 1e-5f) * g1v[tid];
    scl1[tid] = s1;
    shf1[tid] = be1v[tid] + (b1v[tid] - rm1v[tid]) * s1;
    float s2 = rsqrtf(rv2v[tid] + 1e-5f) * g2v[tid];
    scl2[tid] = s2;
    shf2[tid] = be2v[tid] + (b2v[tid] - rm2v[tid]) * s2;
  }
  if (tid == 0) *minid = 128;
  __syncthreads();

  // ---- PH-A: edge atomics only ----
#pragma unroll
  for (int j = 0; j < 2; ++j) {
    atomicAdd(&cntW[ed[j] * 16 + (es[j] >> 3)], 1u << (4 * (es[j] & 7)));
    atomicAdd(&deg[ed[j]], 1u);
    conn[es[j]] = 1u;
    conn[ed[j]] = 1u;
  }
  __syncthreads();

  // ---- PH-B: W1 frag loads + An decode + csumE + dis/minid + G0 ----
  long wb0[8], wb1[8];                           // W1 frags (L2-hot)
#pragma unroll
  for (int ks = 0; ks < 8; ++ks) {
    wb0[ks] = *(const long*)(g_wf + (nt0 + 0) * 4096 + ks * 512 + lane * 8);
    wb1[ks] = *(const long*)(g_wf + (nt0 + 1) * 4096 + ks * 512 + lane * 8);
  }
  {
    int dr = tid >> 4;                           // base row 0..31
    int q8 = tid & 15;                           // col-group (8 cols)
    int s0 = q8 * 8;
    uint4 dg0 = *(const uint4*)(deg + s0);
    uint4 dg1 = *(const uint4*)(deg + s0 + 4);
    float ds8[8] = {rsqrtf((float)dg0.x), rsqrtf((float)dg0.y),
                    rsqrtf((float)dg0.z), rsqrtf((float)dg0.w),
                    rsqrtf((float)dg1.x), rsqrtf((float)dg1.y),
                    rsqrtf((float)dg1.z), rsqrtf((float)dg1.w)};
#pragma unroll
    for (int rr = 0; rr < 4; ++rr) {
      int row = dr + 32 * rr;
      float dd = rsqrtf((float)deg[row]);
      unsigned w = cntW[row * 16 + q8];
      float v[8];
#pragma unroll
      for (int i = 0; i < 8; ++i)
        v[i] = (float)((w >> (4 * i)) & 15u) * dd * ds8[i];
      if (row >= s0 && row < s0 + 8) v[row - s0] += dd * dd;   // self loop
      uint2 o;
      o.x = pk4(v[0], v[1], v[2], v[3]);
      o.y = pk4(v[4], v[5], v[6], v[7]);
      *(uint2*)(AnB + swz8(row, s0)) = o;
    }
  }
#pragma unroll
  for (int j = 0; j < 2; ++j)
    atomicAdd(&csumE[es[j]],
              rsqrtf((float)deg[es[j]]) * rsqrtf((float)deg[ed[j]]));
  if (tid < 128) {
    dis[tid] = rsqrtf((float)deg[tid]);
    if (conn[tid]) atomicMin(minid, tid);
  }
  {  // G0: XW1^T -> X0 ; A-fragments converted from registers (no Y0 pass)
    long af[8];
#pragma unroll
    for (int ks = 0; ks < 8; ++ks) af[ks] = pk8(xa[ks], xb[ks]);
    f32x16 c0 = {}, c1 = {};
#pragma unroll
    for (int ks = 0; ks < 8; ++ks) {
      c0 = MFMA8(af[ks], wb0[ks], c0);
      c1 = MFMA8(af[ks], wb1[ks], c1);
    }
#pragma unroll
    for (int n = 0; n < 2; ++n) {
      int f = (nt0 + n) * 32 + l31;
      const f32x16& c = n ? c1 : c0;
#pragma unroll
      for (int q = 0; q < 4; ++q)
        *(unsigned*)(X0 + swz8(f, mt * 32 + q * 8 + hi * 4)) =
            pk4(c[q * 4 + 0], c[q * 4 + 1], c[q * 4 + 2], c[q * 4 + 3]);
    }
  }
  __syncthreads();

  // ---- G1: (A@XW1)^T = X0 x An -> BN1+ReLU -> Y0[d][f] ----
  {
    long af[8], b0[8], b1[8];
#pragma unroll
    for (int ks = 0; ks < 8; ++ks) {
      af[ks] = *(const long*)(X0 + swz8(mt * 32 + l31, ks * 16 + hi * 8));
      b0[ks] = *(const long*)(AnB + swz8((nt0 + 0) * 32 + l31, ks * 16 + hi * 8));
      b1[ks] = *(const long*)(AnB + swz8((nt0 + 1) * 32 + l31, ks * 16 + hi * 8));
    }
    f32x16 c0 = {}, c1 = {};
#pragma unroll
    for (int ks = 0; ks < 8; ++ks) {
      c0 = MFMA8(af[ks], b0[ks], c0);
      c1 = MFMA8(af[ks], b1[ks], c1);
    }
#pragma unroll
    for (int n = 0; n < 2; ++n) {
      int d = (nt0 + n) * 32 + l31;
      const f32x16& c = n ? c1 : c0;
#pragma unroll
      for (int q = 0; q < 4; ++q) {
        int f0 = mt * 32 + q * 8 + hi * 4;
        f32x4 s4 = *(const f32x4*)(scl1 + f0);
        f32x4 h4 = *(const f32x4*)(shf1 + f0);
        *(unsigned*)(Y0 + swz8(d, f0)) =
            pk4(fmaxf(c[q * 4 + 0] * s4[0] + h4[0], 0.f),
                fmaxf(c[q * 4 + 1] * s4[1] + h4[1], 0.f),
                fmaxf(c[q * 4 + 2] * s4[2] + h4[2], 0.f),
                fmaxf(c[q * 4 + 3] * s4[3] + h4[3], 0.f));
      }
    }
  }
  __syncthreads();

  // ---- G2: Ht2 = (H1 @ W2)^T : Y0 x W2 -> X0[fo][node] ----
  {
    long w20[8], w21[8];
#pragma unroll
    for (int ks = 0; ks < 8; ++ks) {
      w20[ks] = *(const long*)(g_wf + 16384 + (nt0 + 0) * 4096 + ks * 512 + lane * 8);
      w21[ks] = *(const long*)(g_wf + 16384 + (nt0 + 1) * 4096 + ks * 512 + lane * 8);
    }
    long af[8];
#pragma unroll
    for (int ks = 0; ks < 8; ++ks)
      af[ks] = *(const long*)(Y0 + swz8(mt * 32 + l31, ks * 16 + hi * 8));
    f32x16 c0 = {}, c1 = {};
#pragma unroll
    for (int ks = 0; ks < 8; ++ks) {
      c0 = MFMA8(af[ks], w20[ks], c0);
      c1 = MFMA8(af[ks], w21[ks], c1);
    }
#pragma unroll
    for (int n = 0; n < 2; ++n) {
      int f = (nt0 + n) * 32 + l31;
      const f32x16& c = n ? c1 : c0;
#pragma unroll
      for (int q = 0; q < 4; ++q)
        *(unsigned*)(X0 + swz8(f, mt * 32 + q * 8 + hi * 4)) =
            pk4(c[q * 4 + 0], c[q * 4 + 1], c[q * 4 + 2], c[q * 4 + 3]);
    }
  }
  __syncthreads();

  // ---- G3: (A@H2)^T = X0 x An -> BN2+ReLU+colsum-weight -> vred ----
  {
    long af[8], b0[8], b1[8];
#pragma unroll
    for (int ks = 0; ks < 8; ++ks) {
      af[ks] = *(const long*)(X0 + swz8(mt * 32 + l31, ks * 16 + hi * 8));
      b0[ks] = *(const long*)(AnB + swz8((nt0 + 0) * 32 + l31, ks * 16 + hi * 8));
      b1[ks] = *(const long*)(AnB + swz8((nt0 + 1) * 32 + l31, ks * 16 + hi * 8));
    }
    f32x16 c0 = {}, c1 = {};
#pragma unroll
    for (int ks = 0; ks < 8; ++ks) {
      c0 = MFMA8(af[ks], b0[ks], c0);
      c1 = MFMA8(af[ks], b1[ks], c1);
    }
    int nA = (nt0 + 0) * 32 + l31, nB = (nt0 + 1) * 32 + l31;
    float dvA = dis[nA], dvB = dis[nB];
    float csA = csumE[nA] + dvA * dvA;
    float csB = csumE[nB] + dvB * dvB;
#pragma unroll
    for (int q = 0; q < 4; ++q) {
      int f0 = mt * 32 + q * 8 + hi * 4;
      f32x4 s4 = *(const f32x4*)(scl2 + f0);
      f32x4 h4 = *(const f32x4*)(shf2 + f0);
#pragma unroll
      for (int j = 0; j < 4; ++j) {
        float s = csA * fmaxf(c0[q * 4 + j] * s4[j] + h4[j], 0.f) +
                  csB * fmaxf(c1[q * 4 + j] * s4[j] + h4[j], 0.f);
        s += __shfl_xor(s, 1, 32);
        s += __shfl_xor(s, 2, 32);
        s += __shfl_xor(s, 4, 32);
        s += __shfl_xor(s, 8, 32);
        s += __shfl_xor(s, 16, 32);
        if (l31 == 0) atomicAdd(&vred[f0 + j], s);
      }
    }
  }
  __syncthreads();

  // ---- OUT (fused matvec + mask): tid<128 does the full 128-sum ----
  if (tid < 128) {
    float acc = 0.f;
#pragma unroll 8
    for (int f4 = 0; f4 < 32; ++f4) {
      f32x4 vr = *(const f32x4*)(vred + f4 * 4);        // broadcast LDS read
      acc += vr[0] * W3g[(f4 * 4 + 0) * 128 + tid];     // coalesced over tid
      acc += vr[1] * W3g[(f4 * 4 + 1) * 128 + tid];
      acc += vr[2] * W3g[(f4 * 4 + 2) * 128 + tid];
      acc += vr[3] * W3g[(f4 * 4 + 3) * 128 + tid];
    }
    bool msk = (conn[tid] != 0u) && (tid != *minid);
    float val = acc * (1.0f / 128.0f) + b3v[tid];
    out[(size_t)g * 128 + tid] = msk ? NEGV : val;
  }
}

extern "C" void kernel_launch(void* const* d_in, const int* in_sizes, int n_in,
                              void* d_out, int out_size, void* d_ws, size_t ws_size,
                              hipStream_t stream) {
  (void)in_sizes; (void)n_in; (void)out_size; (void)d_ws; (void)ws_size;
  const float* x   = (const float*)d_in[0];
  const int*   ei  = (const int*)d_in[1];
  // d_in[2] = batch (unused; graphs are contiguous 128-node blocks)
  const float* W1  = (const float*)d_in[3];
  const float* b1  = (const float*)d_in[4];
  const float* g1  = (const float*)d_in[5];
  const float* be1 = (const float*)d_in[6];
  const float* rm1 = (const float*)d_in[7];
  const float* rv1 = (const float*)d_in[8];
  const float* W2  = (const float*)d_in[9];
  const float* b2  = (const float*)d_in[10];
  const float* g2  = (const float*)d_in[11];
  const float* be2 = (const float*)d_in[12];
  const float* rm2 = (const float*)d_in[13];
  const float* rv2 = (const float*)d_in[14];
  const float* W3  = (const float*)d_in[15];
  const float* b3  = (const float*)d_in[16];

  prep_w<<<dim3(16), dim3(256), 0, stream>>>(W1, W2);
  gcn_all<<<dim3(NGRAPH), dim3(512), LDS_MAIN, stream>>>(
      x, ei, b1, g1, be1, rm1, rv1, b2, g2, be2, rm2, rv2, W3, b3,
      (float*)d_out);
}

// Round 17
// 31.450 us; speedup vs baseline: 1.1364x; 1.1364x over previous
//
#include <hip/hip_runtime.h>
#include <hip/hip_bf16.h>

// Fused 3-layer GCN + mean-pool + mask, FP8(e4m3), single main kernel.
//   K0 prep_w: W1,W2 -> fragment-ordered fp8 in device-global g_wf (16 WGs)
//   K1 gcn_all: x-stream + A-build + 4 GEMMs + BN + pool + mask, one WG/graph
// Round-17: REVERT to round-14's kernel (best verified: 31.5us).
//   r15 (atomic-contention split, x-overlap restructure): flat -> refuted.
//   r16 (register-direct G0 A-operand): 35.7us -> refuted (uncoalesced x).
// Structure: 6 barriers (P0 | atomics+x-cvt | An-decode+G0 | G1 | G2 | G3 |
// OUT), 512 thr, __launch_bounds__(512,4) -> 128 VGPR, 2 WG/CU, explicit
// fragment-array preloads per GEMM (one waitcnt per phase, not sixteen).
//
// LDS (62468 B): An[0,16K) fp8 swz | Y0[16K,32K) | X0[32K,48K) |
//   cnt[48K,56K) u32[2048] | misc @56K+1.5K

#define NGRAPH 512
#define EPG 1024
#define NEDGE (NGRAPH * EPG)
#define NEGV -10000000000.0f
#define LDS_MAIN 62468

typedef float f32x16 __attribute__((ext_vector_type(16)));
typedef float f32x4  __attribute__((ext_vector_type(4)));

#define MFMA8(a, b, c) __builtin_amdgcn_mfma_f32_32x32x16_fp8_fp8(a, b, c, 0, 0, 0)

__device__ unsigned char g_wf[32768];   // fp8 W1/W2 fragment buffer

// 128B rows; XOR row into the 8B-slot bits -> 2-way max on b64 reads
__device__ __forceinline__ unsigned swz8(unsigned row, unsigned byte_in_row) {
  return ((row << 7) + byte_in_row) ^ ((row & 15u) << 3);
}

__device__ __forceinline__ unsigned pk4(float a, float b, float c, float d) {
  int r = __builtin_amdgcn_cvt_pk_fp8_f32(a, b, 0, false);
  r = __builtin_amdgcn_cvt_pk_fp8_f32(c, d, r, true);
  return (unsigned)r;
}

// W [fi][fo] f32 -> fragment-ordered fp8 W^T, 8B per (layer,nt,ks,lane)
__global__ void prep_w(const float* __restrict__ W1, const float* __restrict__ W2) {
  int gid = blockIdx.x * 256 + threadIdx.x;     // 0..4095, 8 fp8 each
  int lyr = gid >> 11, r = gid & 2047;
  int lane = r & 63, ks = (r >> 6) & 7, nt = r >> 9;
  const float* W = lyr ? W2 : W1;
  int fo = nt * 32 + (lane & 31);
  int k0 = ks * 16 + (lane >> 5) * 8;
  uint2 o;
  o.x = pk4(W[(k0 + 0) * 128 + fo], W[(k0 + 1) * 128 + fo],
            W[(k0 + 2) * 128 + fo], W[(k0 + 3) * 128 + fo]);
  o.y = pk4(W[(k0 + 4) * 128 + fo], W[(k0 + 5) * 128 + fo],
            W[(k0 + 6) * 128 + fo], W[(k0 + 7) * 128 + fo]);
  ((uint2*)g_wf)[gid] = o;
}

__global__ __launch_bounds__(512, 4) void gcn_all(
    const float* __restrict__ x, const int* __restrict__ ei,
    const float* __restrict__ b1v, const float* __restrict__ g1v,
    const float* __restrict__ be1v, const float* __restrict__ rm1v,
    const float* __restrict__ rv1v,
    const float* __restrict__ b2v, const float* __restrict__ g2v,
    const float* __restrict__ be2v, const float* __restrict__ rm2v,
    const float* __restrict__ rv2v,
    const float* __restrict__ W3g, const float* __restrict__ b3v,
    float* __restrict__ out) {
  extern __shared__ char sm[];
  char* AnB = sm;                                // fp8 A_norm[128][128] swz
  char* Y0  = sm + 16384;                        // ping buffer
  char* X0  = sm + 32768;                        // pong buffer
  unsigned* cntW  = (unsigned*)(sm + 49152);     // u4 edge counts [2048 words]
  float*    dis   = (float*)(sm + 57344);
  unsigned* deg   = (unsigned*)(sm + 57856);
  unsigned* conn  = (unsigned*)(sm + 58368);
  float*    csumE = (float*)(sm + 58880);        // edge part of column sum
  float*    scl1  = (float*)(sm + 59392);
  float*    shf1  = (float*)(sm + 59904);
  float*    scl2  = (float*)(sm + 60416);
  float*    shf2  = (float*)(sm + 60928);
  float*    vred  = (float*)(sm + 61440);
  int*      minid = (int*)(sm + 62464);

  const int tid = threadIdx.x;                   // 0..511, 8 waves
  const int g   = blockIdx.x;
  const int lane = tid & 63;
  const int wid  = tid >> 6;                     // 0..7
  const int l31  = lane & 31;
  const int hi   = lane >> 5;
  const int mt   = wid >> 1;                     // A-row tile 0..3
  const int nt0  = (wid & 1) * 2;                // B tiles nt0, nt0+1

  // ---- kernel-top global loads (longest latency first: x, then ei, W1) ----
  const f32x4* xg = (const f32x4*)(x + (size_t)g * 128 * 128);
  f32x4 xr[8];
#pragma unroll
  for (int j = 0; j < 8; ++j) xr[j] = xg[tid + 512 * j];
  int es[2], ed[2];
#pragma unroll
  for (int j = 0; j < 2; ++j) {
    int e = g * EPG + tid + 512 * j;
    es[j] = ei[e] & 127;
    ed[j] = ei[NEDGE + e] & 127;
  }
  long wb0[8], wb1[8];                           // W1 fragments (held to PH-B)
#pragma unroll
  for (int ks = 0; ks < 8; ++ks) {
    wb0[ks] = *(const long*)(g_wf + (nt0 + 0) * 4096 + ks * 512 + lane * 8);
    wb1[ks] = *(const long*)(g_wf + (nt0 + 1) * 4096 + ks * 512 + lane * 8);
  }

  // ---- P0: zero cnt, init misc + BN params (no x dependency) ----
  {
    uint4 z; z.x = 0; z.y = 0; z.z = 0; z.w = 0;
    ((uint4*)cntW)[tid] = z;
  }
  if (tid < 128) {
    deg[tid] = 1u; conn[tid] = 0u; csumE[tid] = 0.f; vred[tid] = 0.f;
    float s1 = rsqrtf(rv1v[tid] + 1e-5f) * g1v[tid];
    scl1[tid] = s1;
    shf1[tid] = be1v[tid] + (b1v[tid] - rm1v[tid]) * s1;
    float s2 = rsqrtf(rv2v[tid] + 1e-5f) * g2v[tid];
    scl2[tid] = s2;
    shf2[tid] = be2v[tid] + (b2v[tid] - rm2v[tid]) * s2;
  }
  if (tid == 0) *minid = 128;
  __syncthreads();

  // ---- PH-A: edge atomics + x -> Y0 (HBM wait hides under atomics) ----
#pragma unroll
  for (int j = 0; j < 2; ++j) {
    atomicAdd(&cntW[ed[j] * 16 + (es[j] >> 3)], 1u << (4 * (es[j] & 7)));
    atomicAdd(&deg[ed[j]], 1u);
    conn[es[j]] = 1u;
    conn[ed[j]] = 1u;
  }
#pragma unroll
  for (int j = 0; j < 8; ++j) {
    int k = tid + 512 * j;
    *(unsigned*)(Y0 + swz8(k >> 5, (k & 31) * 4)) =
        pk4(xr[j][0], xr[j][1], xr[j][2], xr[j][3]);
  }
  __syncthreads();

  // ---- PH-B: An decode (4 rows x 8 cols) + dis + csumE + minid + G0 ----
  {
    int dr = tid >> 4;                           // base row 0..31
    int q8 = tid & 15;                           // col-group (8 cols)
    int s0 = q8 * 8;
    uint4 dg0 = *(const uint4*)(deg + s0);
    uint4 dg1 = *(const uint4*)(deg + s0 + 4);
    float ds8[8] = {rsqrtf((float)dg0.x), rsqrtf((float)dg0.y),
                    rsqrtf((float)dg0.z), rsqrtf((float)dg0.w),
                    rsqrtf((float)dg1.x), rsqrtf((float)dg1.y),
                    rsqrtf((float)dg1.z), rsqrtf((float)dg1.w)};
#pragma unroll
    for (int rr = 0; rr < 4; ++rr) {
      int row = dr + 32 * rr;
      float dd = rsqrtf((float)deg[row]);
      unsigned w = cntW[row * 16 + q8];
      float v[8];
#pragma unroll
      for (int i = 0; i < 8; ++i)
        v[i] = (float)((w >> (4 * i)) & 15u) * dd * ds8[i];
      if (row >= s0 && row < s0 + 8) v[row - s0] += dd * dd;   // self loop
      uint2 o;
      o.x = pk4(v[0], v[1], v[2], v[3]);
      o.y = pk4(v[4], v[5], v[6], v[7]);
      *(uint2*)(AnB + swz8(row, s0)) = o;
    }
  }
#pragma unroll
  for (int j = 0; j < 2; ++j)
    atomicAdd(&csumE[es[j]],
              rsqrtf((float)deg[es[j]]) * rsqrtf((float)deg[ed[j]]));
  if (tid < 128) {
    dis[tid] = rsqrtf((float)deg[tid]);
    if (conn[tid]) atomicMin(minid, tid);
  }
  {  // G0: XW1^T = Y0 x W1 -> X0  (wb0/wb1 preloaded at kernel top)
    long af[8];
#pragma unroll
    for (int ks = 0; ks < 8; ++ks)
      af[ks] = *(const long*)(Y0 + swz8(mt * 32 + l31, ks * 16 + hi * 8));
    f32x16 c0 = {}, c1 = {};
#pragma unroll
    for (int ks = 0; ks < 8; ++ks) {
      c0 = MFMA8(af[ks], wb0[ks], c0);
      c1 = MFMA8(af[ks], wb1[ks], c1);
    }
#pragma unroll
    for (int n = 0; n < 2; ++n) {
      int f = (nt0 + n) * 32 + l31;
      const f32x16& c = n ? c1 : c0;
#pragma unroll
      for (int q = 0; q < 4; ++q)
        *(unsigned*)(X0 + swz8(f, mt * 32 + q * 8 + hi * 4)) =
            pk4(c[q * 4 + 0], c[q * 4 + 1], c[q * 4 + 2], c[q * 4 + 3]);
    }
  }
  __syncthreads();

  // ---- G1: (A@XW1)^T = X0 x An -> BN1+ReLU -> Y0[d][f] ----
  {
    long af[8], b0[8], b1[8];
#pragma unroll
    for (int ks = 0; ks < 8; ++ks) {
      af[ks] = *(const long*)(X0 + swz8(mt * 32 + l31, ks * 16 + hi * 8));
      b0[ks] = *(const long*)(AnB + swz8((nt0 + 0) * 32 + l31, ks * 16 + hi * 8));
      b1[ks] = *(const long*)(AnB + swz8((nt0 + 1) * 32 + l31, ks * 16 + hi * 8));
    }
    f32x16 c0 = {}, c1 = {};
#pragma unroll
    for (int ks = 0; ks < 8; ++ks) {
      c0 = MFMA8(af[ks], b0[ks], c0);
      c1 = MFMA8(af[ks], b1[ks], c1);
    }
#pragma unroll
    for (int n = 0; n < 2; ++n) {
      int d = (nt0 + n) * 32 + l31;
      const f32x16& c = n ? c1 : c0;
#pragma unroll
      for (int q = 0; q < 4; ++q) {
        int f0 = mt * 32 + q * 8 + hi * 4;
        f32x4 s4 = *(const f32x4*)(scl1 + f0);
        f32x4 h4 = *(const f32x4*)(shf1 + f0);
        *(unsigned*)(Y0 + swz8(d, f0)) =
            pk4(fmaxf(c[q * 4 + 0] * s4[0] + h4[0], 0.f),
                fmaxf(c[q * 4 + 1] * s4[1] + h4[1], 0.f),
                fmaxf(c[q * 4 + 2] * s4[2] + h4[2], 0.f),
                fmaxf(c[q * 4 + 3] * s4[3] + h4[3], 0.f));
      }
    }
  }
  __syncthreads();

  // ---- G2: Ht2 = (H1 @ W2)^T : Y0 x W2 -> X0[fo][node] ----
  {
    long w20[8], w21[8];
#pragma unroll
    for (int ks = 0; ks < 8; ++ks) {
      w20[ks] = *(const long*)(g_wf + 16384 + (nt0 + 0) * 4096 + ks * 512 + lane * 8);
      w21[ks] = *(const long*)(g_wf + 16384 + (nt0 + 1) * 4096 + ks * 512 + lane * 8);
    }
    long af[8];
#pragma unroll
    for (int ks = 0; ks < 8; ++ks)
      af[ks] = *(const long*)(Y0 + swz8(mt * 32 + l31, ks * 16 + hi * 8));
    f32x16 c0 = {}, c1 = {};
#pragma unroll
    for (int ks = 0; ks < 8; ++ks) {
      c0 = MFMA8(af[ks], w20[ks], c0);
      c1 = MFMA8(af[ks], w21[ks], c1);
    }
#pragma unroll
    for (int n = 0; n < 2; ++n) {
      int f = (nt0 + n) * 32 + l31;
      const f32x16& c = n ? c1 : c0;
#pragma unroll
      for (int q = 0; q < 4; ++q)
        *(unsigned*)(X0 + swz8(f, mt * 32 + q * 8 + hi * 4)) =
            pk4(c[q * 4 + 0], c[q * 4 + 1], c[q * 4 + 2], c[q * 4 + 3]);
    }
  }
  __syncthreads();

  // ---- G3: (A@H2)^T = X0 x An -> BN2+ReLU+colsum-weight -> vred ----
  {
    long af[8], b0[8], b1[8];
#pragma unroll
    for (int ks = 0; ks < 8; ++ks) {
      af[ks] = *(const long*)(X0 + swz8(mt * 32 + l31, ks * 16 + hi * 8));
      b0[ks] = *(const long*)(AnB + swz8((nt0 + 0) * 32 + l31, ks * 16 + hi * 8));
      b1[ks] = *(const long*)(AnB + swz8((nt0 + 1) * 32 + l31, ks * 16 + hi * 8));
    }
    f32x16 c0 = {}, c1 = {};
#pragma unroll
    for (int ks = 0; ks < 8; ++ks) {
      c0 = MFMA8(af[ks], b0[ks], c0);
      c1 = MFMA8(af[ks], b1[ks], c1);
    }
    int nA = (nt0 + 0) * 32 + l31, nB = (nt0 + 1) * 32 + l31;
    float dvA = dis[nA], dvB = dis[nB];
    float csA = csumE[nA] + dvA * dvA;
    float csB = csumE[nB] + dvB * dvB;
#pragma unroll
    for (int q = 0; q < 4; ++q) {
      int f0 = mt * 32 + q * 8 + hi * 4;
      f32x4 s4 = *(const f32x4*)(scl2 + f0);
      f32x4 h4 = *(const f32x4*)(shf2 + f0);
#pragma unroll
      for (int j = 0; j < 4; ++j) {
        float s = csA * fmaxf(c0[q * 4 + j] * s4[j] + h4[j], 0.f) +
                  csB * fmaxf(c1[q * 4 + j] * s4[j] + h4[j], 0.f);
        s += __shfl_xor(s, 1, 32);
        s += __shfl_xor(s, 2, 32);
        s += __shfl_xor(s, 4, 32);
        s += __shfl_xor(s, 8, 32);
        s += __shfl_xor(s, 16, 32);
        if (l31 == 0) atomicAdd(&vred[f0 + j], s);
      }
    }
  }
  __syncthreads();

  // ---- OUT (fused matvec + mask): tid<128 does the full 128-sum ----
  if (tid < 128) {
    float acc = 0.f;
#pragma unroll 8
    for (int f4 = 0; f4 < 32; ++f4) {
      f32x4 vr = *(const f32x4*)(vred + f4 * 4);       // broadcast LDS read
      acc += vr[0] * W3g[(f4 * 4 + 0) * 128 + tid];     // coalesced over tid
      acc += vr[1] * W3g[(f4 * 4 + 1) * 128 + tid];
      acc += vr[2] * W3g[(f4 * 4 + 2) * 128 + tid];
      acc += vr[3] * W3g[(f4 * 4 + 3) * 128 + tid];
    }
    bool msk = (conn[tid] != 0u) && (tid != *minid);
    float val = acc * (1.0f / 128.0f) + b3v[tid];
    out[(size_t)g * 128 + tid] = msk ? NEGV : val;
  }
}

extern "C" void kernel_launch(void* const* d_in, const int* in_sizes, int n_in,
                              void* d_out, int out_size, void* d_ws, size_t ws_size,
                              hipStream_t stream) {
  (void)in_sizes; (void)n_in; (void)out_size; (void)d_ws; (void)ws_size;
  const float* x   = (const float*)d_in[0];
  const int*   ei  = (const int*)d_in[1];
  // d_in[2] = batch (unused; graphs are contiguous 128-node blocks)
  const float* W1  = (const float*)d_in[3];
  const float* b1  = (const float*)d_in[4];
  const float* g1  = (const float*)d_in[5];
  const float* be1 = (const float*)d_in[6];
  const float* rm1 = (const float*)d_in[7];
  const float* rv1 = (const float*)d_in[8];
  const float* W2  = (const float*)d_in[9];
  const float* b2  = (const float*)d_in[10];
  const float* g2  = (const float*)d_in[11];
  const float* be2 = (const float*)d_in[12];
  const float* rm2 = (const float*)d_in[13];
  const float* rv2 = (const float*)d_in[14];
  const float* W3  = (const float*)d_in[15];
  const float* b3  = (const float*)d_in[16];

  prep_w<<<dim3(16), dim3(256), 0, stream>>>(W1, W2);
  gcn_all<<<dim3(NGRAPH), dim3(512), LDS_MAIN, stream>>>(
      x, ei, b1, g1, be1, rm1, rv1, b2, g2, be2, rm2, rv2, W3, b3,
      (float*)d_out);
}